// Round 5
// baseline (810.371 us; speedup 1.0000x reference)
//
#include <hip/hip_runtime.h>

#define NTOK 343
#define NPAD 352
#define DIM 384
#define NHEAD 12
#define HDIM 32
#define NWIN 64
#define BATCH 128
#define SCALE 0.17677669529663687f
#define NN 117649  // 343*343

typedef __attribute__((ext_vector_type(8))) short bf16x8;
typedef __attribute__((ext_vector_type(4))) short bf16x4;
typedef __attribute__((ext_vector_type(4))) float f32x4;
typedef __attribute__((ext_vector_type(4))) int i32x4;

static __device__ inline short f2bf(float f) {
  union { float f; unsigned u; } v; v.f = f;
  unsigned r = v.u + 0x7fffu + ((v.u >> 16) & 1u);
  return (short)(r >> 16);
}
static __device__ inline float bf2f(short s) {
  union { unsigned u; float f; } v; v.u = ((unsigned)(unsigned short)s) << 16;
  return v.f;
}
// pack two f32 -> one int of 2 bf16 (lo in low half), RTNE via f2bf
static __device__ inline int pack2(float lo, float hi) {
  return (int)((unsigned)(unsigned short)f2bf(lo) |
               ((unsigned)(unsigned short)f2bf(hi) << 16));
}

#define MFMA16(a, b, c) __builtin_amdgcn_mfma_f32_16x16x32_bf16((a), (b), (c), 0, 0, 0)

// ---------- kernel 0a: bias_t[h][m][n] = table[rpi[n][m]][h] ----------------
__global__ __launch_bounds__(256) void bias_tr_kernel(
    const float* __restrict__ table, const int* __restrict__ rpi,
    float* __restrict__ bias_t) {
  int idx = blockIdx.x * 256 + threadIdx.x;
  const int total = NHEAD * NN;
  if (idx >= total) return;
  int h = idx / NN;
  int rem = idx - h * NN;
  int m = rem / NTOK;
  int n = rem - m * NTOK;
  bias_t[idx] = table[rpi[n * NTOK + m] * NHEAD + h];
}

// ---------- kernel 0b: mask_t[w][m][n] = mask[w][n][m] (LDS tiled) ----------
__global__ __launch_bounds__(256) void mask_tr_kernel(
    const float* __restrict__ in, float* __restrict__ out) {
  __shared__ float tile[32][33];
  const int w = blockIdx.z;
  const int ti = blockIdx.y * 32, tj = blockIdx.x * 32;
  const int tx = threadIdx.x & 31, ty4 = (threadIdx.x >> 5) * 4;
  const float* mw = in + (size_t)w * NN;
  float* ow = out + (size_t)w * NN;
#pragma unroll
  for (int r = 0; r < 4; ++r) {
    int i = ti + ty4 + r, j = tj + tx;
    if (i < NTOK && j < NTOK) tile[ty4 + r][tx] = mw[i * NTOK + j];
  }
  __syncthreads();
#pragma unroll
  for (int r = 0; r < 4; ++r) {
    int i = tj + ty4 + r, j = ti + tx;
    if (i < NTOK && j < NTOK) ow[i * NTOK + j] = tile[tx][ty4 + r];
  }
}

// ---------- kernel 1: kv = skip @ w_kv^T + b_kv -> K_ws/V_ws (bf16) ---------
__global__ __launch_bounds__(256) void kv_proj_kernel(
    const float* __restrict__ X, const float* __restrict__ W,
    const float* __restrict__ bkv, short* __restrict__ Kws,
    short* __restrict__ Vws) {
  __shared__ short As[128][40];
  __shared__ short Bs[128][40];
  const int tid = threadIdx.x;
  const int n0 = blockIdx.x * 128;
  const int m0 = blockIdx.y * 128;
  const int lane = tid & 63;
  const int wave = tid >> 6;
  const int wm = (wave >> 1) * 64;
  const int wn = (wave & 1) * 64;
  const int lr = lane & 15;
  const int lk = (lane >> 4) * 8;
  const int c4 = (tid & 7) * 4;
  const int rbase = tid >> 3;
  const f32x4 zero4 = {0.f, 0.f, 0.f, 0.f};

  f32x4 acc[4][4];
#pragma unroll
  for (int m = 0; m < 4; ++m)
#pragma unroll
    for (int n = 0; n < 4; ++n) acc[m][n] = zero4;

  for (int kk = 0; kk < 12; ++kk) {
    __syncthreads();
#pragma unroll
    for (int i = 0; i < 4; ++i) {
      int row = rbase + i * 32;
      f32x4 v = *(const f32x4*)(X + (size_t)(m0 + row) * DIM + kk * 32 + c4);
      bf16x4 s4;
#pragma unroll
      for (int j = 0; j < 4; ++j) s4[j] = f2bf(v[j]);
      *(bf16x4*)(&As[row][c4]) = s4;
    }
#pragma unroll
    for (int i = 0; i < 4; ++i) {
      int row = rbase + i * 32;
      f32x4 v = *(const f32x4*)(W + (size_t)(n0 + row) * DIM + kk * 32 + c4);
      bf16x4 s4;
#pragma unroll
      for (int j = 0; j < 4; ++j) s4[j] = f2bf(v[j]);
      *(bf16x4*)(&Bs[row][c4]) = s4;
    }
    __syncthreads();
    bf16x8 af[4], bf[4];
#pragma unroll
    for (int m = 0; m < 4; ++m) af[m] = *(const bf16x8*)(&As[wm + m * 16 + lr][lk]);
#pragma unroll
    for (int n = 0; n < 4; ++n) bf[n] = *(const bf16x8*)(&Bs[wn + n * 16 + lr][lk]);
#pragma unroll
    for (int m = 0; m < 4; ++m)
#pragma unroll
      for (int n = 0; n < 4; ++n) acc[m][n] = MFMA16(af[m], bf[n], acc[m][n]);
  }

  const int rq = (lane >> 4) * 4;
#pragma unroll
  for (int n = 0; n < 4; ++n) {
    int gcol = n0 + wn + n * 16 + lr;
    float bias = bkv[gcol];
    int c = (gcol >= DIM) ? (gcol - DIM) : gcol;  // gcol % 384
    int h = c >> 5;
    int hd = c & 31;
    short* dst = (gcol < DIM) ? Kws : Vws;
#pragma unroll
    for (int m = 0; m < 4; ++m) {
#pragma unroll
      for (int r = 0; r < 4; ++r) {
        int grow = m0 + wm + m * 16 + rq + r;
        int bb = grow / NTOK;
        int tok = grow - bb * NTOK;
        dst[(((size_t)bb * NHEAD + h) * NTOK + tok) * HDIM + hd] =
            f2bf(acc[m][n][r] + bias);
      }
    }
  }
}

// ---------- kernel 2: fused attention per (b, h) — swapped-QK^T form --------
// S^T = mfma(K, Q): lane (lr,lg) holds S[q=lr][m=16j+4lg+r].
// Softmax in registers (2 shfls per reduce). P normalized then packed (f2bf,
// RTNE — proven numerics). V stored at pi-permuted columns so PV's MFMA
// k-order matches P's natural register order. No P LDS buffer.
__global__ __launch_bounds__(256, 3) void attn_kernel(
    const float* __restrict__ x_up, const float* __restrict__ mask_t,
    const float* __restrict__ bias_t, const short* __restrict__ Kws,
    const short* __restrict__ Vws, short* __restrict__ attn_out) {
  __shared__ short Ksm[NPAD][40];      // K[key][ch], row stride 80B
  __shared__ short Vp[HDIM][NPAD + 8]; // V^T[ch][pi(key)], row stride 720B
  const int bid = blockIdx.x;
  const int b = bid / NHEAD;
  const int h = bid - b * NHEAD;
  const int win = b & (NWIN - 1);
  const int tid = threadIdx.x;
  const int wave = tid >> 6;
  const int lane = tid & 63;
  const int lr = lane & 15;
  const int lg = lane >> 4;
  const int koff = lg * 8;
  const f32x4 zero4 = {0.f, 0.f, 0.f, 0.f};

  const short* Kb = Kws + ((size_t)b * NHEAD + h) * NTOK * HDIM;
  const short* Vb = Vws + ((size_t)b * NHEAD + h) * NTOK * HDIM;
  {
    const int c8 = (tid & 3) * 8;
    const int rb = tid >> 2;
    const bf16x8 z8 = {0, 0, 0, 0, 0, 0, 0, 0};
#pragma unroll
    for (int r0 = 0; r0 < 384; r0 += 64) {
      int row = r0 + rb;
      if (row < NPAD) {
        bf16x8 kv = z8;
        if (row < NTOK) kv = *(const bf16x8*)(Kb + row * HDIM + c8);
        *(bf16x8*)(&Ksm[row][c8]) = kv;
      }
    }
#pragma unroll
    for (int r0 = 0; r0 < 384; r0 += 64) {
      int row = r0 + rb;
      if (row < NPAD) {
        bf16x8 vv = z8;
        if (row < NTOK) vv = *(const bf16x8*)(Vb + row * HDIM + c8);
        // pi(row): k-slot = ((m&16)>>2) | ((m&12)<<1) | (m&3) within 32-block
        int p = (row & ~31) | ((row & 12) << 1) | ((row & 16) >> 2) | (row & 3);
#pragma unroll
        for (int i = 0; i < 8; ++i) Vp[c8 + i][p] = vv[i];
      }
    }
  }
  __syncthreads();

  for (int qt = 0; qt < 6; ++qt) {
    const int q0 = qt * 64 + wave * 16;
    if (q0 >= NTOK) continue;
    const int qn = q0 + lr;
    const int qidx = (qn < NTOK) ? qn : (NTOK - 1);
    // Q B-frag: col=q=lr, k = channel 8*lg+i (clamped row; invalid cols unused)
    bf16x8 qf;
    {
      const float* qp = x_up + ((size_t)b * NTOK + qidx) * DIM + h * HDIM + koff;
      f32x4 v0 = *(const f32x4*)qp;
      f32x4 v1 = *(const f32x4*)(qp + 4);
#pragma unroll
      for (int i = 0; i < 4; ++i) {
        qf[i] = f2bf(v0[i] * SCALE);
        qf[i + 4] = f2bf(v1[i] * SCALE);
      }
    }
    // S^T tiles: s[j] = K_j * Q   (A=K: row=key=lr, k=ch; B=Q)
    f32x4 s[22];
#pragma unroll
    for (int j = 0; j < 22; ++j) {
      bf16x8 kf = *(const bf16x8*)(&Ksm[j * 16 + lr][koff]);
      s[j] = MFMA16(kf, qf, zero4);
    }
    // softmax over m: add bias+mask, row max (2 shfls), exp, sum (2 shfls),
    // normalize BEFORE bf16 pack — exact R2-proven numerics.
    const float* bh = bias_t + (size_t)h * NN + qidx;
    const float* mh = mask_t + (size_t)win * NN + qidx;
    const int mb = 4 * lg * NTOK;
    float mx = -1e30f;
#pragma unroll
    for (int j = 0; j < 22; ++j) {
#pragma unroll
      for (int r = 0; r < 4; ++r) {
        int moff = mb + (j * 16 + r) * NTOK;
        float lv = s[j][r] + bh[moff] + mh[moff];
        if (j == 21 && (4 * lg + r) >= 7) lv = -1e30f;  // m >= 343 invalid
        s[j][r] = lv;
        mx = fmaxf(mx, lv);
      }
    }
    mx = fmaxf(mx, __shfl_xor(mx, 16));
    mx = fmaxf(mx, __shfl_xor(mx, 32));
    float sum = 0.f;
#pragma unroll
    for (int j = 0; j < 22; ++j) {
#pragma unroll
      for (int r = 0; r < 4; ++r) {
        float p = __expf(s[j][r] - mx);
        s[j][r] = p;
        sum += p;
      }
    }
    sum += __shfl_xor(sum, 16);
    sum += __shfl_xor(sum, 32);
    const float inv = 1.0f / sum;
    i32x4 up4[11];
#pragma unroll
    for (int j = 0; j < 22; ++j) {
      up4[j >> 1][(j & 1) * 2 + 0] = pack2(s[j][0] * inv, s[j][1] * inv);
      up4[j >> 1][(j & 1) * 2 + 1] = pack2(s[j][2] * inv, s[j][3] * inv);
    }

    // O^T = V^T_pi * P : A-frag from Vp (b128), B-frag = packed P registers
    f32x4 o0 = zero4;
    f32x4 o1 = zero4;
#pragma unroll
    for (int kt = 0; kt < 11; ++kt) {
      bf16x8 pf = __builtin_bit_cast(bf16x8, up4[kt]);
      bf16x8 a0 = *(const bf16x8*)(&Vp[lr][kt * 32 + koff]);
      bf16x8 a1 = *(const bf16x8*)(&Vp[16 + lr][kt * 32 + koff]);
      o0 = MFMA16(a0, pf, o0);
      o1 = MFMA16(a1, pf, o1);
    }
    // lane holds O[q=lr][d = 4*lg + r (+16)]; already normalized; pack+store
    if (qn < NTOK) {
      short* op = attn_out + ((size_t)b * NTOK + qn) * DIM + h * HDIM + 4 * lg;
      *(int*)(op + 0) = pack2(o0[0], o0[1]);
      *(int*)(op + 2) = pack2(o0[2], o0[3]);
      *(int*)(op + 16) = pack2(o1[0], o1[1]);
      *(int*)(op + 18) = pack2(o1[2], o1[3]);
    }
  }
}

// ---------- kernel 3: out = (attn + pos) @ w_proj^T + b_proj ----------------
__global__ __launch_bounds__(256) void out_proj_kernel(
    const short* __restrict__ Xa, const float* __restrict__ pos,
    const float* __restrict__ W, const float* __restrict__ bpr,
    float* __restrict__ out) {
  __shared__ short As[128][40];
  __shared__ short Bs[128][40];
  const int tid = threadIdx.x;
  const int n0 = blockIdx.x * 128;
  const int m0 = blockIdx.y * 128;
  const int lane = tid & 63;
  const int wave = tid >> 6;
  const int wm = (wave >> 1) * 64;
  const int wn = (wave & 1) * 64;
  const int lr = lane & 15;
  const int lk = (lane >> 4) * 8;
  const int c4 = (tid & 7) * 4;
  const int rbase = tid >> 3;
  const f32x4 zero4 = {0.f, 0.f, 0.f, 0.f};

  f32x4 acc[4][4];
#pragma unroll
  for (int m = 0; m < 4; ++m)
#pragma unroll
    for (int n = 0; n < 4; ++n) acc[m][n] = zero4;

  for (int kk = 0; kk < 12; ++kk) {
    __syncthreads();
#pragma unroll
    for (int i = 0; i < 4; ++i) {
      int row = rbase + i * 32;
      size_t goff = (size_t)(m0 + row) * DIM + kk * 32 + c4;
      bf16x4 a4 = *(const bf16x4*)(Xa + goff);
      f32x4 p = *(const f32x4*)(pos + goff);
      bf16x4 s4;
#pragma unroll
      for (int j = 0; j < 4; ++j) s4[j] = f2bf(bf2f(a4[j]) + p[j]);
      *(bf16x4*)(&As[row][c4]) = s4;
    }
#pragma unroll
    for (int i = 0; i < 4; ++i) {
      int row = rbase + i * 32;
      f32x4 v = *(const f32x4*)(W + (size_t)(n0 + row) * DIM + kk * 32 + c4);
      bf16x4 s4;
#pragma unroll
      for (int j = 0; j < 4; ++j) s4[j] = f2bf(v[j]);
      *(bf16x4*)(&Bs[row][c4]) = s4;
    }
    __syncthreads();
    bf16x8 af[4], bf[4];
#pragma unroll
    for (int m = 0; m < 4; ++m) af[m] = *(const bf16x8*)(&As[wm + m * 16 + lr][lk]);
#pragma unroll
    for (int n = 0; n < 4; ++n) bf[n] = *(const bf16x8*)(&Bs[wn + n * 16 + lr][lk]);
#pragma unroll
    for (int m = 0; m < 4; ++m)
#pragma unroll
      for (int n = 0; n < 4; ++n) acc[m][n] = MFMA16(af[m], bf[n], acc[m][n]);
  }

  const int rq = (lane >> 4) * 4;
#pragma unroll
  for (int n = 0; n < 4; ++n) {
    int gcol = n0 + wn + n * 16 + lr;
    float bias = bpr[gcol];
#pragma unroll
    for (int m = 0; m < 4; ++m) {
#pragma unroll
      for (int r = 0; r < 4; ++r) {
        int grow = m0 + wm + m * 16 + rq + r;
        out[(size_t)grow * DIM + gcol] = acc[m][n][r] + bias;
      }
    }
  }
}

extern "C" void kernel_launch(void* const* d_in, const int* in_sizes, int n_in,
                              void* d_out, int out_size, void* d_ws, size_t ws_size,
                              hipStream_t stream) {
  const float* skip = (const float*)d_in[0];
  const float* x_up = (const float*)d_in[1];
  const float* pos = (const float*)d_in[2];
  const float* mask = (const float*)d_in[3];
  const float* w_kv = (const float*)d_in[4];
  const float* b_kv = (const float*)d_in[5];
  const float* w_proj = (const float*)d_in[6];
  const float* b_proj = (const float*)d_in[7];
  const float* bias_table = (const float*)d_in[8];
  const int* rpi = (const int*)d_in[9];
  float* out = (float*)d_out;

  char* ws = (char*)d_ws;
  const size_t kv_bytes = (size_t)BATCH * NHEAD * NTOK * HDIM * 2;  // 33,718,272
  const size_t bias_bytes = (size_t)NHEAD * NN * 4;                 //  5,647,152
  const size_t mask_bytes = (size_t)NWIN * NN * 4;                  // 30,118,144
  short* Kws = (short*)ws;
  short* Vws = (short*)(ws + kv_bytes);
  float* bias_t = (float*)(ws + 2 * kv_bytes);
  float* mask_t = (float*)(ws + 2 * kv_bytes + bias_bytes);
  short* attn_ws = (short*)(ws + 2 * kv_bytes + bias_bytes + mask_bytes);

  bias_tr_kernel<<<dim3((NHEAD * NN + 255) / 256), dim3(256), 0, stream>>>(
      bias_table, rpi, bias_t);
  mask_tr_kernel<<<dim3(11, 11, NWIN), dim3(256), 0, stream>>>(mask, mask_t);
  kv_proj_kernel<<<dim3(6, 343), dim3(256), 0, stream>>>(skip, w_kv, b_kv, Kws, Vws);
  attn_kernel<<<dim3(BATCH * NHEAD), dim3(256), 0, stream>>>(x_up, mask_t, bias_t,
                                                             Kws, Vws, attn_ws);
  out_proj_kernel<<<dim3(3, 343), dim3(256), 0, stream>>>(attn_ws, pos, w_proj,
                                                          b_proj, out);
}

// Round 6
// 750.215 us; speedup vs baseline: 1.0802x; 1.0802x over previous
//
#include <hip/hip_runtime.h>

#define NTOK 343
#define NPAD 352
#define DIM 384
#define NHEAD 12
#define HDIM 32
#define NWIN 64
#define BATCH 128
#define SCALE 0.17677669529663687f
#define NN 117649  // 343*343

typedef __attribute__((ext_vector_type(8))) short bf16x8;
typedef __attribute__((ext_vector_type(4))) short bf16x4;
typedef __attribute__((ext_vector_type(4))) float f32x4;
typedef __attribute__((ext_vector_type(4))) int i32x4;

static __device__ inline short f2bf(float f) {
  union { float f; unsigned u; } v; v.f = f;
  unsigned r = v.u + 0x7fffu + ((v.u >> 16) & 1u);
  return (short)(r >> 16);
}
static __device__ inline float bf2f(short s) {
  union { unsigned u; float f; } v; v.u = ((unsigned)(unsigned short)s) << 16;
  return v.f;
}
// pack two f32 -> one int of 2 bf16 (lo in low half), RTNE via f2bf
static __device__ inline int pack2(float lo, float hi) {
  return (int)((unsigned)(unsigned short)f2bf(lo) |
               ((unsigned)(unsigned short)f2bf(hi) << 16));
}

#define MFMA16(a, b, c) __builtin_amdgcn_mfma_f32_16x16x32_bf16((a), (b), (c), 0, 0, 0)

// ---------- kernel 0a: bias_t[h][m][n] = table[rpi[n][m]][h] ----------------
__global__ __launch_bounds__(256) void bias_tr_kernel(
    const float* __restrict__ table, const int* __restrict__ rpi,
    float* __restrict__ bias_t) {
  int idx = blockIdx.x * 256 + threadIdx.x;
  const int total = NHEAD * NN;
  if (idx >= total) return;
  int h = idx / NN;
  int rem = idx - h * NN;
  int m = rem / NTOK;
  int n = rem - m * NTOK;
  bias_t[idx] = table[rpi[n * NTOK + m] * NHEAD + h];
}

// ---------- kernel 0b: mask_t[w][m][n] = mask[w][n][m] (LDS tiled) ----------
__global__ __launch_bounds__(256) void mask_tr_kernel(
    const float* __restrict__ in, float* __restrict__ out) {
  __shared__ float tile[32][33];
  const int w = blockIdx.z;
  const int ti = blockIdx.y * 32, tj = blockIdx.x * 32;
  const int tx = threadIdx.x & 31, ty4 = (threadIdx.x >> 5) * 4;
  const float* mw = in + (size_t)w * NN;
  float* ow = out + (size_t)w * NN;
#pragma unroll
  for (int r = 0; r < 4; ++r) {
    int i = ti + ty4 + r, j = tj + tx;
    if (i < NTOK && j < NTOK) tile[ty4 + r][tx] = mw[i * NTOK + j];
  }
  __syncthreads();
#pragma unroll
  for (int r = 0; r < 4; ++r) {
    int i = tj + ty4 + r, j = ti + tx;
    if (i < NTOK && j < NTOK) ow[i * NTOK + j] = tile[tx][ty4 + r];
  }
}

// ---------- kernel 1: kv = skip @ w_kv^T + b_kv -> K_ws/V_ws (bf16) ---------
__global__ __launch_bounds__(256) void kv_proj_kernel(
    const float* __restrict__ X, const float* __restrict__ W,
    const float* __restrict__ bkv, short* __restrict__ Kws,
    short* __restrict__ Vws) {
  __shared__ short As[128][40];
  __shared__ short Bs[128][40];
  const int tid = threadIdx.x;
  const int n0 = blockIdx.x * 128;
  const int m0 = blockIdx.y * 128;
  const int lane = tid & 63;
  const int wave = tid >> 6;
  const int wm = (wave >> 1) * 64;
  const int wn = (wave & 1) * 64;
  const int lr = lane & 15;
  const int lk = (lane >> 4) * 8;
  const int c4 = (tid & 7) * 4;
  const int rbase = tid >> 3;
  const f32x4 zero4 = {0.f, 0.f, 0.f, 0.f};

  f32x4 acc[4][4];
#pragma unroll
  for (int m = 0; m < 4; ++m)
#pragma unroll
    for (int n = 0; n < 4; ++n) acc[m][n] = zero4;

  for (int kk = 0; kk < 12; ++kk) {
    __syncthreads();
#pragma unroll
    for (int i = 0; i < 4; ++i) {
      int row = rbase + i * 32;
      f32x4 v = *(const f32x4*)(X + (size_t)(m0 + row) * DIM + kk * 32 + c4);
      bf16x4 s4;
#pragma unroll
      for (int j = 0; j < 4; ++j) s4[j] = f2bf(v[j]);
      *(bf16x4*)(&As[row][c4]) = s4;
    }
#pragma unroll
    for (int i = 0; i < 4; ++i) {
      int row = rbase + i * 32;
      f32x4 v = *(const f32x4*)(W + (size_t)(n0 + row) * DIM + kk * 32 + c4);
      bf16x4 s4;
#pragma unroll
      for (int j = 0; j < 4; ++j) s4[j] = f2bf(v[j]);
      *(bf16x4*)(&Bs[row][c4]) = s4;
    }
    __syncthreads();
    bf16x8 af[4], bf[4];
#pragma unroll
    for (int m = 0; m < 4; ++m) af[m] = *(const bf16x8*)(&As[wm + m * 16 + lr][lk]);
#pragma unroll
    for (int n = 0; n < 4; ++n) bf[n] = *(const bf16x8*)(&Bs[wn + n * 16 + lr][lk]);
#pragma unroll
    for (int m = 0; m < 4; ++m)
#pragma unroll
      for (int n = 0; n < 4; ++n) acc[m][n] = MFMA16(af[m], bf[n], acc[m][n]);
  }

  const int rq = (lane >> 4) * 4;
#pragma unroll
  for (int n = 0; n < 4; ++n) {
    int gcol = n0 + wn + n * 16 + lr;
    float bias = bkv[gcol];
    int c = (gcol >= DIM) ? (gcol - DIM) : gcol;  // gcol % 384
    int h = c >> 5;
    int hd = c & 31;
    short* dst = (gcol < DIM) ? Kws : Vws;
#pragma unroll
    for (int m = 0; m < 4; ++m) {
#pragma unroll
      for (int r = 0; r < 4; ++r) {
        int grow = m0 + wm + m * 16 + rq + r;
        int bb = grow / NTOK;
        int tok = grow - bb * NTOK;
        dst[(((size_t)bb * NHEAD + h) * NTOK + tok) * HDIM + hd] =
            f2bf(acc[m][n][r] + bias);
      }
    }
  }
}

// ---------- kernel 2: fused attention per (b, h) — swapped-QK^T form --------
// Win-grouped XCD swizzle: bid = j*8 + xcd, win = xcd*8 + j/24 — all 24
// blocks sharing mask_t[win] land on ONE XCD, temporally adjacent (L2 reuse).
__global__ __launch_bounds__(256, 2) void attn_kernel(
    const float* __restrict__ x_up, const float* __restrict__ mask_t,
    const float* __restrict__ bias_t, const short* __restrict__ Kws,
    const short* __restrict__ Vws, short* __restrict__ attn_out) {
  __shared__ short Ksm[NPAD][40];      // K[key][ch], row stride 80B
  __shared__ short Vp[HDIM][NPAD + 8]; // V^T[ch][pi(key)], row stride 720B
  const int bid = blockIdx.x;
  const int xcd = bid & 7;
  const int jj = bid >> 3;                 // 0..191
  const int win = xcd * 8 + jj / 24;       // 0..63, pinned to xcd
  const int rep = jj - (jj / 24) * 24;     // 0..23
  const int h = rep % NHEAD;
  const int b = win + ((rep >= NHEAD) ? 64 : 0);
  const int tid = threadIdx.x;
  const int wave = tid >> 6;
  const int lane = tid & 63;
  const int lr = lane & 15;
  const int lg = lane >> 4;
  const int koff = lg * 8;
  const f32x4 zero4 = {0.f, 0.f, 0.f, 0.f};

  const short* Kb = Kws + ((size_t)b * NHEAD + h) * NTOK * HDIM;
  const short* Vb = Vws + ((size_t)b * NHEAD + h) * NTOK * HDIM;
  {
    const int c8 = (tid & 3) * 8;
    const int rb = tid >> 2;
    const bf16x8 z8 = {0, 0, 0, 0, 0, 0, 0, 0};
#pragma unroll
    for (int r0 = 0; r0 < 384; r0 += 64) {
      int row = r0 + rb;
      if (row < NPAD) {
        bf16x8 kv = z8;
        if (row < NTOK) kv = *(const bf16x8*)(Kb + row * HDIM + c8);
        *(bf16x8*)(&Ksm[row][c8]) = kv;
      }
    }
#pragma unroll
    for (int r0 = 0; r0 < 384; r0 += 64) {
      int row = r0 + rb;
      if (row < NPAD) {
        bf16x8 vv = z8;
        if (row < NTOK) vv = *(const bf16x8*)(Vb + row * HDIM + c8);
        // pi(row): k-slot = ((m&16)>>2) | ((m&12)<<1) | (m&3) within 32-block
        int p = (row & ~31) | ((row & 12) << 1) | ((row & 16) >> 2) | (row & 3);
#pragma unroll
        for (int i = 0; i < 8; ++i) Vp[c8 + i][p] = vv[i];
      }
    }
  }
  __syncthreads();

  for (int qt = 0; qt < 6; ++qt) {
    const int q0 = qt * 64 + wave * 16;
    if (q0 >= NTOK) continue;
    const int qn = q0 + lr;
    const int qidx = (qn < NTOK) ? qn : (NTOK - 1);
    // Q B-frag: col=q=lr, k = channel 8*lg+i (clamped row; invalid cols unused)
    bf16x8 qf;
    {
      const float* qp = x_up + ((size_t)b * NTOK + qidx) * DIM + h * HDIM + koff;
      f32x4 v0 = *(const f32x4*)qp;
      f32x4 v1 = *(const f32x4*)(qp + 4);
#pragma unroll
      for (int i = 0; i < 4; ++i) {
        qf[i] = f2bf(v0[i] * SCALE);
        qf[i + 4] = f2bf(v1[i] * SCALE);
      }
    }
    // S^T tiles: s[j] = K_j * Q   (A=K: row=key=lr, k=ch; B=Q)
    f32x4 s[22];
#pragma unroll
    for (int j = 0; j < 22; ++j) {
      bf16x8 kf = *(const bf16x8*)(&Ksm[j * 16 + lr][koff]);
      s[j] = MFMA16(kf, qf, zero4);
    }
    // softmax over m: add bias+mask, row max (2 shfls), exp, sum (2 shfls),
    // normalize BEFORE bf16 pack.
    const float* bh = bias_t + (size_t)h * NN + qidx;
    const float* mh = mask_t + (size_t)win * NN + qidx;
    const int mb = 4 * lg * NTOK;
    float mx = -1e30f;
#pragma unroll
    for (int j = 0; j < 22; ++j) {
#pragma unroll
      for (int r = 0; r < 4; ++r) {
        int moff = mb + (j * 16 + r) * NTOK;
        float lv = s[j][r] + bh[moff] + mh[moff];
        if (j == 21 && (4 * lg + r) >= 7) lv = -1e30f;  // m >= 343 invalid
        s[j][r] = lv;
        mx = fmaxf(mx, lv);
      }
    }
    mx = fmaxf(mx, __shfl_xor(mx, 16));
    mx = fmaxf(mx, __shfl_xor(mx, 32));
    float sum = 0.f;
#pragma unroll
    for (int j = 0; j < 22; ++j) {
#pragma unroll
      for (int r = 0; r < 4; ++r) {
        float p = __expf(s[j][r] - mx);
        s[j][r] = p;
        sum += p;
      }
    }
    sum += __shfl_xor(sum, 16);
    sum += __shfl_xor(sum, 32);
    const float inv = 1.0f / sum;
    i32x4 up4[11];
#pragma unroll
    for (int j = 0; j < 22; ++j) {
      up4[j >> 1][(j & 1) * 2 + 0] = pack2(s[j][0] * inv, s[j][1] * inv);
      up4[j >> 1][(j & 1) * 2 + 1] = pack2(s[j][2] * inv, s[j][3] * inv);
    }

    // O^T = V^T_pi * P : A-frag from Vp (b128), B-frag = packed P registers
    f32x4 o0 = zero4;
    f32x4 o1 = zero4;
#pragma unroll
    for (int kt = 0; kt < 11; ++kt) {
      bf16x8 pf = __builtin_bit_cast(bf16x8, up4[kt]);
      bf16x8 a0 = *(const bf16x8*)(&Vp[lr][kt * 32 + koff]);
      bf16x8 a1 = *(const bf16x8*)(&Vp[16 + lr][kt * 32 + koff]);
      o0 = MFMA16(a0, pf, o0);
      o1 = MFMA16(a1, pf, o1);
    }
    // lane holds O[q=lr][d = 4*lg + r (+16)]; already normalized; pack+store
    if (qn < NTOK) {
      short* op = attn_out + ((size_t)b * NTOK + qn) * DIM + h * HDIM + 4 * lg;
      *(int*)(op + 0) = pack2(o0[0], o0[1]);
      *(int*)(op + 2) = pack2(o0[2], o0[3]);
      *(int*)(op + 16) = pack2(o1[0], o1[1]);
      *(int*)(op + 18) = pack2(o1[2], o1[3]);
    }
  }
}

// ---------- kernel 3: out = (attn + pos) @ w_proj^T + b_proj ----------------
__global__ __launch_bounds__(256) void out_proj_kernel(
    const short* __restrict__ Xa, const float* __restrict__ pos,
    const float* __restrict__ W, const float* __restrict__ bpr,
    float* __restrict__ out) {
  __shared__ short As[128][40];
  __shared__ short Bs[128][40];
  const int tid = threadIdx.x;
  const int n0 = blockIdx.x * 128;
  const int m0 = blockIdx.y * 128;
  const int lane = tid & 63;
  const int wave = tid >> 6;
  const int wm = (wave >> 1) * 64;
  const int wn = (wave & 1) * 64;
  const int lr = lane & 15;
  const int lk = (lane >> 4) * 8;
  const int c4 = (tid & 7) * 4;
  const int rbase = tid >> 3;
  const f32x4 zero4 = {0.f, 0.f, 0.f, 0.f};

  f32x4 acc[4][4];
#pragma unroll
  for (int m = 0; m < 4; ++m)
#pragma unroll
    for (int n = 0; n < 4; ++n) acc[m][n] = zero4;

  for (int kk = 0; kk < 12; ++kk) {
    __syncthreads();
#pragma unroll
    for (int i = 0; i < 4; ++i) {
      int row = rbase + i * 32;
      size_t goff = (size_t)(m0 + row) * DIM + kk * 32 + c4;
      bf16x4 a4 = *(const bf16x4*)(Xa + goff);
      f32x4 p = *(const f32x4*)(pos + goff);
      bf16x4 s4;
#pragma unroll
      for (int j = 0; j < 4; ++j) s4[j] = f2bf(bf2f(a4[j]) + p[j]);
      *(bf16x4*)(&As[row][c4]) = s4;
    }
#pragma unroll
    for (int i = 0; i < 4; ++i) {
      int row = rbase + i * 32;
      f32x4 v = *(const f32x4*)(W + (size_t)(n0 + row) * DIM + kk * 32 + c4);
      bf16x4 s4;
#pragma unroll
      for (int j = 0; j < 4; ++j) s4[j] = f2bf(v[j]);
      *(bf16x4*)(&Bs[row][c4]) = s4;
    }
    __syncthreads();
    bf16x8 af[4], bf[4];
#pragma unroll
    for (int m = 0; m < 4; ++m) af[m] = *(const bf16x8*)(&As[wm + m * 16 + lr][lk]);
#pragma unroll
    for (int n = 0; n < 4; ++n) bf[n] = *(const bf16x8*)(&Bs[wn + n * 16 + lr][lk]);
#pragma unroll
    for (int m = 0; m < 4; ++m)
#pragma unroll
      for (int n = 0; n < 4; ++n) acc[m][n] = MFMA16(af[m], bf[n], acc[m][n]);
  }

  const int rq = (lane >> 4) * 4;
#pragma unroll
  for (int n = 0; n < 4; ++n) {
    int gcol = n0 + wn + n * 16 + lr;
    float bias = bpr[gcol];
#pragma unroll
    for (int m = 0; m < 4; ++m) {
#pragma unroll
      for (int r = 0; r < 4; ++r) {
        int grow = m0 + wm + m * 16 + rq + r;
        out[(size_t)grow * DIM + gcol] = acc[m][n][r] + bias;
      }
    }
  }
}

extern "C" void kernel_launch(void* const* d_in, const int* in_sizes, int n_in,
                              void* d_out, int out_size, void* d_ws, size_t ws_size,
                              hipStream_t stream) {
  const float* skip = (const float*)d_in[0];
  const float* x_up = (const float*)d_in[1];
  const float* pos = (const float*)d_in[2];
  const float* mask = (const float*)d_in[3];
  const float* w_kv = (const float*)d_in[4];
  const float* b_kv = (const float*)d_in[5];
  const float* w_proj = (const float*)d_in[6];
  const float* b_proj = (const float*)d_in[7];
  const float* bias_table = (const float*)d_in[8];
  const int* rpi = (const int*)d_in[9];
  float* out = (float*)d_out;

  char* ws = (char*)d_ws;
  const size_t kv_bytes = (size_t)BATCH * NHEAD * NTOK * HDIM * 2;  // 33,718,272
  const size_t bias_bytes = (size_t)NHEAD * NN * 4;                 //  5,647,152
  const size_t mask_bytes = (size_t)NWIN * NN * 4;                  // 30,118,144
  short* Kws = (short*)ws;
  short* Vws = (short*)(ws + kv_bytes);
  float* bias_t = (float*)(ws + 2 * kv_bytes);
  float* mask_t = (float*)(ws + 2 * kv_bytes + bias_bytes);
  short* attn_ws = (short*)(ws + 2 * kv_bytes + bias_bytes + mask_bytes);

  bias_tr_kernel<<<dim3((NHEAD * NN + 255) / 256), dim3(256), 0, stream>>>(
      bias_table, rpi, bias_t);
  mask_tr_kernel<<<dim3(11, 11, NWIN), dim3(256), 0, stream>>>(mask, mask_t);
  kv_proj_kernel<<<dim3(6, 343), dim3(256), 0, stream>>>(skip, w_kv, b_kv, Kws, Vws);
  attn_kernel<<<dim3(BATCH * NHEAD), dim3(256), 0, stream>>>(x_up, mask_t, bias_t,
                                                             Kws, Vws, attn_ws);
  out_proj_kernel<<<dim3(3, 343), dim3(256), 0, stream>>>(attn_ws, pos, w_proj,
                                                          b_proj, out);
}

// Round 7
// 394.180 us; speedup vs baseline: 2.0558x; 1.9032x over previous
//
#include <hip/hip_runtime.h>

#define NTOK 343
#define NPAD 352
#define DIM 384
#define NHEAD 12
#define HDIM 32
#define NWIN 64
#define BATCH 128
#define SCALE 0.17677669529663687f
#define NN 117649   // 343*343
#define MG 88       // NPAD/4 m-groups
#define GSTRIDE 1372  // NTOK*4 floats per m-group

typedef __attribute__((ext_vector_type(8))) short bf16x8;
typedef __attribute__((ext_vector_type(4))) short bf16x4;
typedef __attribute__((ext_vector_type(4))) float f32x4;
typedef __attribute__((ext_vector_type(4))) int i32x4;

static __device__ inline short f2bf(float f) {
  union { float f; unsigned u; } v; v.f = f;
  unsigned r = v.u + 0x7fffu + ((v.u >> 16) & 1u);
  return (short)(r >> 16);
}
static __device__ inline float bf2f(short s) {
  union { unsigned u; float f; } v; v.u = ((unsigned)(unsigned short)s) << 16;
  return v.f;
}
// pack two f32 -> one int of 2 bf16 (lo in low half), RTNE via f2bf
static __device__ inline int pack2(float lo, float hi) {
  return (int)((unsigned)(unsigned short)f2bf(lo) |
               ((unsigned)(unsigned short)f2bf(hi) << 16));
}

#define MFMA16(a, b, c) __builtin_amdgcn_mfma_f32_16x16x32_bf16((a), (b), (c), 0, 0, 0)

// ---- kernel 0a: bias_q4[h][g][q][r] = table[rpi[q][g*4+r]][h], pad=-1e30 ----
__global__ __launch_bounds__(256) void bias_pk_kernel(
    const float* __restrict__ table, const int* __restrict__ rpi,
    float* __restrict__ bias_q4) {
  int idx = blockIdx.x * 256 + threadIdx.x;
  const int total = NHEAD * MG * NTOK * 4;
  if (idx >= total) return;
  int r = idx & 3;
  int t = idx >> 2;
  int q = t % NTOK;
  int u = t / NTOK;
  int g = u % MG;
  int h = u / MG;
  int m = g * 4 + r;
  bias_q4[idx] = (m < NTOK) ? table[rpi[q * NTOK + m] * NHEAD + h] : -1e30f;
}

// ---- kernel 0b: mask_q4[w][g][q][r] = mask[w][q][g*4+r], pad=0 --------------
__global__ __launch_bounds__(256) void mask_pk_kernel(
    const float* __restrict__ in, float* __restrict__ mask_q4) {
  int idx = blockIdx.x * 256 + threadIdx.x;
  const int total = NWIN * MG * NTOK * 4;
  if (idx >= total) return;
  int r = idx & 3;
  int t = idx >> 2;
  int q = t % NTOK;
  int u = t / NTOK;
  int g = u % MG;
  int w = u / MG;
  int m = g * 4 + r;
  mask_q4[idx] = (m < NTOK) ? in[(size_t)w * NN + q * NTOK + m] : 0.0f;
}

// ---------- kernel 1: kv = skip @ w_kv^T + b_kv -> K_ws/V_ws (bf16) ---------
__global__ __launch_bounds__(256) void kv_proj_kernel(
    const float* __restrict__ X, const float* __restrict__ W,
    const float* __restrict__ bkv, short* __restrict__ Kws,
    short* __restrict__ Vws) {
  __shared__ short As[128][40];
  __shared__ short Bs[128][40];
  const int tid = threadIdx.x;
  const int n0 = blockIdx.x * 128;
  const int m0 = blockIdx.y * 128;
  const int lane = tid & 63;
  const int wave = tid >> 6;
  const int wm = (wave >> 1) * 64;
  const int wn = (wave & 1) * 64;
  const int lr = lane & 15;
  const int lk = (lane >> 4) * 8;
  const int c4 = (tid & 7) * 4;
  const int rbase = tid >> 3;
  const f32x4 zero4 = {0.f, 0.f, 0.f, 0.f};

  f32x4 acc[4][4];
#pragma unroll
  for (int m = 0; m < 4; ++m)
#pragma unroll
    for (int n = 0; n < 4; ++n) acc[m][n] = zero4;

  for (int kk = 0; kk < 12; ++kk) {
    __syncthreads();
#pragma unroll
    for (int i = 0; i < 4; ++i) {
      int row = rbase + i * 32;
      f32x4 v = *(const f32x4*)(X + (size_t)(m0 + row) * DIM + kk * 32 + c4);
      bf16x4 s4;
#pragma unroll
      for (int j = 0; j < 4; ++j) s4[j] = f2bf(v[j]);
      *(bf16x4*)(&As[row][c4]) = s4;
    }
#pragma unroll
    for (int i = 0; i < 4; ++i) {
      int row = rbase + i * 32;
      f32x4 v = *(const f32x4*)(W + (size_t)(n0 + row) * DIM + kk * 32 + c4);
      bf16x4 s4;
#pragma unroll
      for (int j = 0; j < 4; ++j) s4[j] = f2bf(v[j]);
      *(bf16x4*)(&Bs[row][c4]) = s4;
    }
    __syncthreads();
    bf16x8 af[4], bf[4];
#pragma unroll
    for (int m = 0; m < 4; ++m) af[m] = *(const bf16x8*)(&As[wm + m * 16 + lr][lk]);
#pragma unroll
    for (int n = 0; n < 4; ++n) bf[n] = *(const bf16x8*)(&Bs[wn + n * 16 + lr][lk]);
#pragma unroll
    for (int m = 0; m < 4; ++m)
#pragma unroll
      for (int n = 0; n < 4; ++n) acc[m][n] = MFMA16(af[m], bf[n], acc[m][n]);
  }

  const int rq = (lane >> 4) * 4;
#pragma unroll
  for (int n = 0; n < 4; ++n) {
    int gcol = n0 + wn + n * 16 + lr;
    float bias = bkv[gcol];
    int c = (gcol >= DIM) ? (gcol - DIM) : gcol;  // gcol % 384
    int h = c >> 5;
    int hd = c & 31;
    short* dst = (gcol < DIM) ? Kws : Vws;
#pragma unroll
    for (int m = 0; m < 4; ++m) {
#pragma unroll
      for (int r = 0; r < 4; ++r) {
        int grow = m0 + wm + m * 16 + rq + r;
        int bb = grow / NTOK;
        int tok = grow - bb * NTOK;
        dst[(((size_t)bb * NHEAD + h) * NTOK + tok) * HDIM + hd] =
            f2bf(acc[m][n][r] + bias);
      }
    }
  }
}

// ---------- kernel 2: fused attention per (b, h) — swapped-QK^T form --------
// Win-grouped XCD swizzle (R6-proven): all 24 blocks sharing mask[win] on one
// XCD, temporally adjacent. Bias/mask as f32x4 m-group loads (4x fewer instrs).
// launch_bounds(256,3): VGPR cap 170 so s[22] stays in VGPRs (R6's 80-VGPR
// AGPR-shuffle serialization was the stall).
__global__ __launch_bounds__(256, 3) void attn_kernel(
    const float* __restrict__ x_up, const float* __restrict__ mask_q4,
    const float* __restrict__ bias_q4, const short* __restrict__ Kws,
    const short* __restrict__ Vws, short* __restrict__ attn_out) {
  __shared__ short Ksm[NPAD][40];      // K[key][ch], row stride 80B
  __shared__ short Vp[HDIM][NPAD + 8]; // V^T[ch][pi(key)], row stride 720B
  const int bid = blockIdx.x;
  const int xcd = bid & 7;
  const int jj = bid >> 3;                 // 0..191
  const int win = xcd * 8 + jj / 24;       // 0..63, pinned to xcd
  const int rep = jj - (jj / 24) * 24;     // 0..23
  const int h = rep % NHEAD;
  const int b = win + ((rep >= NHEAD) ? 64 : 0);
  const int tid = threadIdx.x;
  const int wave = tid >> 6;
  const int lane = tid & 63;
  const int lr = lane & 15;
  const int lg = lane >> 4;
  const int koff = lg * 8;
  const f32x4 zero4 = {0.f, 0.f, 0.f, 0.f};

  const short* Kb = Kws + ((size_t)b * NHEAD + h) * NTOK * HDIM;
  const short* Vb = Vws + ((size_t)b * NHEAD + h) * NTOK * HDIM;
  {
    const int c8 = (tid & 3) * 8;
    const int rb = tid >> 2;
    const bf16x8 z8 = {0, 0, 0, 0, 0, 0, 0, 0};
#pragma unroll
    for (int r0 = 0; r0 < 384; r0 += 64) {
      int row = r0 + rb;
      if (row < NPAD) {
        bf16x8 kv = z8;
        if (row < NTOK) kv = *(const bf16x8*)(Kb + row * HDIM + c8);
        *(bf16x8*)(&Ksm[row][c8]) = kv;
      }
    }
#pragma unroll
    for (int r0 = 0; r0 < 384; r0 += 64) {
      int row = r0 + rb;
      if (row < NPAD) {
        bf16x8 vv = z8;
        if (row < NTOK) vv = *(const bf16x8*)(Vb + row * HDIM + c8);
        // pi(row): k-slot = ((m&16)>>2) | ((m&12)<<1) | (m&3) within 32-block
        int p = (row & ~31) | ((row & 12) << 1) | ((row & 16) >> 2) | (row & 3);
#pragma unroll
        for (int i = 0; i < 8; ++i) Vp[c8 + i][p] = vv[i];
      }
    }
  }
  __syncthreads();

  for (int qt = 0; qt < 6; ++qt) {
    const int q0 = qt * 64 + wave * 16;
    if (q0 >= NTOK) continue;
    const int qn = q0 + lr;
    const int qidx = (qn < NTOK) ? qn : (NTOK - 1);
    // Q B-frag: col=q=lr, k = channel 8*lg+i (clamped row; invalid cols unused)
    bf16x8 qf;
    {
      const float* qp = x_up + ((size_t)b * NTOK + qidx) * DIM + h * HDIM + koff;
      f32x4 v0 = *(const f32x4*)qp;
      f32x4 v1 = *(const f32x4*)(qp + 4);
#pragma unroll
      for (int i = 0; i < 4; ++i) {
        qf[i] = f2bf(v0[i] * SCALE);
        qf[i + 4] = f2bf(v1[i] * SCALE);
      }
    }
    // S^T tiles: s[j] = K_j * Q   (A=K: row=key=lr, k=ch; B=Q)
    f32x4 s[22];
#pragma unroll
    for (int j = 0; j < 22; ++j) {
      bf16x8 kf = *(const bf16x8*)(&Ksm[j * 16 + lr][koff]);
      s[j] = MFMA16(kf, qf, zero4);
    }
    // softmax over m: vector bias+mask add (f32x4 loads, pad handles tail),
    // row max (2 shfls), exp, sum (2 shfls), normalize before bf16 pack.
    const float* bq = bias_q4 + (size_t)h * MG * GSTRIDE + (size_t)lg * GSTRIDE +
                      qidx * 4;
    const float* mq = mask_q4 + (size_t)win * MG * GSTRIDE + (size_t)lg * GSTRIDE +
                      qidx * 4;
    float mx = -1e30f;
#pragma unroll
    for (int j = 0; j < 22; ++j) {
      f32x4 bv = *(const f32x4*)(bq + (size_t)j * 4 * GSTRIDE);
      f32x4 mv = *(const f32x4*)(mq + (size_t)j * 4 * GSTRIDE);
      s[j] += bv + mv;
#pragma unroll
      for (int r = 0; r < 4; ++r) mx = fmaxf(mx, s[j][r]);
    }
    mx = fmaxf(mx, __shfl_xor(mx, 16));
    mx = fmaxf(mx, __shfl_xor(mx, 32));
    float sum = 0.f;
#pragma unroll
    for (int j = 0; j < 22; ++j) {
#pragma unroll
      for (int r = 0; r < 4; ++r) {
        float p = __expf(s[j][r] - mx);
        s[j][r] = p;
        sum += p;
      }
    }
    sum += __shfl_xor(sum, 16);
    sum += __shfl_xor(sum, 32);
    const float inv = 1.0f / sum;
    i32x4 up4[11];
#pragma unroll
    for (int j = 0; j < 22; ++j) {
      up4[j >> 1][(j & 1) * 2 + 0] = pack2(s[j][0] * inv, s[j][1] * inv);
      up4[j >> 1][(j & 1) * 2 + 1] = pack2(s[j][2] * inv, s[j][3] * inv);
    }

    // O^T = V^T_pi * P : A-frag from Vp (b128), B-frag = packed P registers
    f32x4 o0 = zero4;
    f32x4 o1 = zero4;
#pragma unroll
    for (int kt = 0; kt < 11; ++kt) {
      bf16x8 pf = __builtin_bit_cast(bf16x8, up4[kt]);
      bf16x8 a0 = *(const bf16x8*)(&Vp[lr][kt * 32 + koff]);
      bf16x8 a1 = *(const bf16x8*)(&Vp[16 + lr][kt * 32 + koff]);
      o0 = MFMA16(a0, pf, o0);
      o1 = MFMA16(a1, pf, o1);
    }
    // lane holds O[q=lr][d = 4*lg + r (+16)]; already normalized; pack+store
    if (qn < NTOK) {
      short* op = attn_out + ((size_t)b * NTOK + qn) * DIM + h * HDIM + 4 * lg;
      *(int*)(op + 0) = pack2(o0[0], o0[1]);
      *(int*)(op + 2) = pack2(o0[2], o0[3]);
      *(int*)(op + 16) = pack2(o1[0], o1[1]);
      *(int*)(op + 18) = pack2(o1[2], o1[3]);
    }
  }
}

// ---------- kernel 3: out = (attn + pos) @ w_proj^T + b_proj ----------------
__global__ __launch_bounds__(256) void out_proj_kernel(
    const short* __restrict__ Xa, const float* __restrict__ pos,
    const float* __restrict__ W, const float* __restrict__ bpr,
    float* __restrict__ out) {
  __shared__ short As[128][40];
  __shared__ short Bs[128][40];
  const int tid = threadIdx.x;
  const int n0 = blockIdx.x * 128;
  const int m0 = blockIdx.y * 128;
  const int lane = tid & 63;
  const int wave = tid >> 6;
  const int wm = (wave >> 1) * 64;
  const int wn = (wave & 1) * 64;
  const int lr = lane & 15;
  const int lk = (lane >> 4) * 8;
  const int c4 = (tid & 7) * 4;
  const int rbase = tid >> 3;
  const f32x4 zero4 = {0.f, 0.f, 0.f, 0.f};

  f32x4 acc[4][4];
#pragma unroll
  for (int m = 0; m < 4; ++m)
#pragma unroll
    for (int n = 0; n < 4; ++n) acc[m][n] = zero4;

  for (int kk = 0; kk < 12; ++kk) {
    __syncthreads();
#pragma unroll
    for (int i = 0; i < 4; ++i) {
      int row = rbase + i * 32;
      size_t goff = (size_t)(m0 + row) * DIM + kk * 32 + c4;
      bf16x4 a4 = *(const bf16x4*)(Xa + goff);
      f32x4 p = *(const f32x4*)(pos + goff);
      bf16x4 s4;
#pragma unroll
      for (int j = 0; j < 4; ++j) s4[j] = f2bf(bf2f(a4[j]) + p[j]);
      *(bf16x4*)(&As[row][c4]) = s4;
    }
#pragma unroll
    for (int i = 0; i < 4; ++i) {
      int row = rbase + i * 32;
      f32x4 v = *(const f32x4*)(W + (size_t)(n0 + row) * DIM + kk * 32 + c4);
      bf16x4 s4;
#pragma unroll
      for (int j = 0; j < 4; ++j) s4[j] = f2bf(v[j]);
      *(bf16x4*)(&Bs[row][c4]) = s4;
    }
    __syncthreads();
    bf16x8 af[4], bf[4];
#pragma unroll
    for (int m = 0; m < 4; ++m) af[m] = *(const bf16x8*)(&As[wm + m * 16 + lr][lk]);
#pragma unroll
    for (int n = 0; n < 4; ++n) bf[n] = *(const bf16x8*)(&Bs[wn + n * 16 + lr][lk]);
#pragma unroll
    for (int m = 0; m < 4; ++m)
#pragma unroll
      for (int n = 0; n < 4; ++n) acc[m][n] = MFMA16(af[m], bf[n], acc[m][n]);
  }

  const int rq = (lane >> 4) * 4;
#pragma unroll
  for (int n = 0; n < 4; ++n) {
    int gcol = n0 + wn + n * 16 + lr;
    float bias = bpr[gcol];
#pragma unroll
    for (int m = 0; m < 4; ++m) {
#pragma unroll
      for (int r = 0; r < 4; ++r) {
        int grow = m0 + wm + m * 16 + rq + r;
        out[(size_t)grow * DIM + gcol] = acc[m][n][r] + bias;
      }
    }
  }
}

extern "C" void kernel_launch(void* const* d_in, const int* in_sizes, int n_in,
                              void* d_out, int out_size, void* d_ws, size_t ws_size,
                              hipStream_t stream) {
  const float* skip = (const float*)d_in[0];
  const float* x_up = (const float*)d_in[1];
  const float* pos = (const float*)d_in[2];
  const float* mask = (const float*)d_in[3];
  const float* w_kv = (const float*)d_in[4];
  const float* b_kv = (const float*)d_in[5];
  const float* w_proj = (const float*)d_in[6];
  const float* b_proj = (const float*)d_in[7];
  const float* bias_table = (const float*)d_in[8];
  const int* rpi = (const int*)d_in[9];
  float* out = (float*)d_out;

  char* ws = (char*)d_ws;
  const size_t kv_bytes = (size_t)BATCH * NHEAD * NTOK * HDIM * 2;   // 33,718,272
  const size_t bias_bytes = (size_t)NHEAD * MG * NTOK * 4 * 4;       //  5,795,328
  const size_t mask_bytes = (size_t)NWIN * MG * NTOK * 4 * 4;        // 30,908,416
  short* Kws = (short*)ws;
  short* Vws = (short*)(ws + kv_bytes);
  float* bias_q4 = (float*)(ws + 2 * kv_bytes);
  float* mask_q4 = (float*)(ws + 2 * kv_bytes + bias_bytes);
  short* attn_ws = (short*)(ws + 2 * kv_bytes + bias_bytes + mask_bytes);

  const int bias_total = NHEAD * MG * NTOK * 4;
  const int mask_total = NWIN * MG * NTOK * 4;
  bias_pk_kernel<<<dim3((bias_total + 255) / 256), dim3(256), 0, stream>>>(
      bias_table, rpi, bias_q4);
  mask_pk_kernel<<<dim3((mask_total + 255) / 256), dim3(256), 0, stream>>>(
      mask, mask_q4);
  kv_proj_kernel<<<dim3(6, 343), dim3(256), 0, stream>>>(skip, w_kv, b_kv, Kws, Vws);
  attn_kernel<<<dim3(BATCH * NHEAD), dim3(256), 0, stream>>>(x_up, mask_q4, bias_q4,
                                                             Kws, Vws, attn_ws);
  out_proj_kernel<<<dim3(3, 343), dim3(256), 0, stream>>>(attn_ws, pos, w_proj,
                                                          b_proj, out);
}

// Round 8
// 387.156 us; speedup vs baseline: 2.0931x; 1.0181x over previous
//
#include <hip/hip_runtime.h>

#define NTOK 343
#define NPAD 352
#define DIM 384
#define NHEAD 12
#define HDIM 32
#define NWIN 64
#define BATCH 128
#define SCALE 0.17677669529663687f
#define NN 117649   // 343*343
#define MG 88       // NPAD/4 m-groups
#define GSTRIDE 1372  // NTOK*4 floats per m-group

typedef __attribute__((ext_vector_type(8))) short bf16x8;
typedef __attribute__((ext_vector_type(4))) short bf16x4;
typedef __attribute__((ext_vector_type(4))) float f32x4;
typedef __attribute__((ext_vector_type(4))) int i32x4;

static __device__ inline short f2bf(float f) {
  union { float f; unsigned u; } v; v.f = f;
  unsigned r = v.u + 0x7fffu + ((v.u >> 16) & 1u);
  return (short)(r >> 16);
}
static __device__ inline float bf2f(short s) {
  union { unsigned u; float f; } v; v.u = ((unsigned)(unsigned short)s) << 16;
  return v.f;
}
// pack two f32 -> one int of 2 bf16 (lo in low half), RTNE via f2bf
static __device__ inline int pack2(float lo, float hi) {
  return (int)((unsigned)(unsigned short)f2bf(lo) |
               ((unsigned)(unsigned short)f2bf(hi) << 16));
}

#define MFMA16(a, b, c) __builtin_amdgcn_mfma_f32_16x16x32_bf16((a), (b), (c), 0, 0, 0)

// ---- kernel 0a: bias_q4[h][g][q][r] = table[rpi[q][g*4+r]][h], pad=-1e30 ----
__global__ __launch_bounds__(256) void bias_pk_kernel(
    const float* __restrict__ table, const int* __restrict__ rpi,
    float* __restrict__ bias_q4) {
  int idx = blockIdx.x * 256 + threadIdx.x;
  const int total = NHEAD * MG * NTOK * 4;
  if (idx >= total) return;
  int r = idx & 3;
  int t = idx >> 2;
  int q = t % NTOK;
  int u = t / NTOK;
  int g = u % MG;
  int h = u / MG;
  int m = g * 4 + r;
  bias_q4[idx] = (m < NTOK) ? table[rpi[q * NTOK + m] * NHEAD + h] : -1e30f;
}

// ---- kernel 0b: mask_q4[w][g][q][r] = mask[w][q][g*4+r], pad=0 --------------
__global__ __launch_bounds__(256) void mask_pk_kernel(
    const float* __restrict__ in, float* __restrict__ mask_q4) {
  int idx = blockIdx.x * 256 + threadIdx.x;
  const int total = NWIN * MG * NTOK * 4;
  if (idx >= total) return;
  int r = idx & 3;
  int t = idx >> 2;
  int q = t % NTOK;
  int u = t / NTOK;
  int g = u % MG;
  int w = u / MG;
  int m = g * 4 + r;
  mask_q4[idx] = (m < NTOK) ? in[(size_t)w * NN + q * NTOK + m] : 0.0f;
}

// ---------- kernel 1: kv = skip @ w_kv^T + b_kv -> K_ws/V_ws (bf16) ---------
__global__ __launch_bounds__(256) void kv_proj_kernel(
    const float* __restrict__ X, const float* __restrict__ W,
    const float* __restrict__ bkv, short* __restrict__ Kws,
    short* __restrict__ Vws) {
  __shared__ short As[128][40];
  __shared__ short Bs[128][40];
  const int tid = threadIdx.x;
  const int n0 = blockIdx.x * 128;
  const int m0 = blockIdx.y * 128;
  const int lane = tid & 63;
  const int wave = tid >> 6;
  const int wm = (wave >> 1) * 64;
  const int wn = (wave & 1) * 64;
  const int lr = lane & 15;
  const int lk = (lane >> 4) * 8;
  const int c4 = (tid & 7) * 4;
  const int rbase = tid >> 3;
  const f32x4 zero4 = {0.f, 0.f, 0.f, 0.f};

  f32x4 acc[4][4];
#pragma unroll
  for (int m = 0; m < 4; ++m)
#pragma unroll
    for (int n = 0; n < 4; ++n) acc[m][n] = zero4;

  for (int kk = 0; kk < 12; ++kk) {
    __syncthreads();
#pragma unroll
    for (int i = 0; i < 4; ++i) {
      int row = rbase + i * 32;
      f32x4 v = *(const f32x4*)(X + (size_t)(m0 + row) * DIM + kk * 32 + c4);
      bf16x4 s4;
#pragma unroll
      for (int j = 0; j < 4; ++j) s4[j] = f2bf(v[j]);
      *(bf16x4*)(&As[row][c4]) = s4;
    }
#pragma unroll
    for (int i = 0; i < 4; ++i) {
      int row = rbase + i * 32;
      f32x4 v = *(const f32x4*)(W + (size_t)(n0 + row) * DIM + kk * 32 + c4);
      bf16x4 s4;
#pragma unroll
      for (int j = 0; j < 4; ++j) s4[j] = f2bf(v[j]);
      *(bf16x4*)(&Bs[row][c4]) = s4;
    }
    __syncthreads();
    bf16x8 af[4], bf[4];
#pragma unroll
    for (int m = 0; m < 4; ++m) af[m] = *(const bf16x8*)(&As[wm + m * 16 + lr][lk]);
#pragma unroll
    for (int n = 0; n < 4; ++n) bf[n] = *(const bf16x8*)(&Bs[wn + n * 16 + lr][lk]);
#pragma unroll
    for (int m = 0; m < 4; ++m)
#pragma unroll
      for (int n = 0; n < 4; ++n) acc[m][n] = MFMA16(af[m], bf[n], acc[m][n]);
  }

  const int rq = (lane >> 4) * 4;
#pragma unroll
  for (int n = 0; n < 4; ++n) {
    int gcol = n0 + wn + n * 16 + lr;
    float bias = bkv[gcol];
    int c = (gcol >= DIM) ? (gcol - DIM) : gcol;  // gcol % 384
    int h = c >> 5;
    int hd = c & 31;
    short* dst = (gcol < DIM) ? Kws : Vws;
#pragma unroll
    for (int m = 0; m < 4; ++m) {
#pragma unroll
      for (int r = 0; r < 4; ++r) {
        int grow = m0 + wm + m * 16 + rq + r;
        int bb = grow / NTOK;
        int tok = grow - bb * NTOK;
        dst[(((size_t)bb * NHEAD + h) * NTOK + tok) * HDIM + hd] =
            f2bf(acc[m][n][r] + bias);
      }
    }
  }
}

// ---------- kernel 2: fused attention per (b, h) — swapped-QK^T form --------
// Win-grouped XCD swizzle (R6-proven): all 24 blocks sharing mask[win] on one
// XCD, temporally adjacent. Bias/mask as f32x4 m-group loads (4x fewer instrs).
// launch_bounds(256,3): VGPR cap 170 so s[22] stays in VGPRs (R6's 80-VGPR
// AGPR-shuffle serialization was the stall).
__global__ __launch_bounds__(256, 3) void attn_kernel(
    const float* __restrict__ x_up, const float* __restrict__ mask_q4,
    const float* __restrict__ bias_q4, const short* __restrict__ Kws,
    const short* __restrict__ Vws, short* __restrict__ attn_out) {
  __shared__ short Ksm[NPAD][40];      // K[key][ch], row stride 80B
  __shared__ short Vp[HDIM][NPAD + 8]; // V^T[ch][pi(key)], row stride 720B
  const int bid = blockIdx.x;
  const int xcd = bid & 7;
  const int jj = bid >> 3;                 // 0..191
  const int win = xcd * 8 + jj / 24;       // 0..63, pinned to xcd
  const int rep = jj - (jj / 24) * 24;     // 0..23
  const int h = rep % NHEAD;
  const int b = win + ((rep >= NHEAD) ? 64 : 0);
  const int tid = threadIdx.x;
  const int wave = tid >> 6;
  const int lane = tid & 63;
  const int lr = lane & 15;
  const int lg = lane >> 4;
  const int koff = lg * 8;
  const f32x4 zero4 = {0.f, 0.f, 0.f, 0.f};

  const short* Kb = Kws + ((size_t)b * NHEAD + h) * NTOK * HDIM;
  const short* Vb = Vws + ((size_t)b * NHEAD + h) * NTOK * HDIM;
  {
    const int c8 = (tid & 3) * 8;
    const int rb = tid >> 2;
    const bf16x8 z8 = {0, 0, 0, 0, 0, 0, 0, 0};
#pragma unroll
    for (int r0 = 0; r0 < 384; r0 += 64) {
      int row = r0 + rb;
      if (row < NPAD) {
        bf16x8 kv = z8;
        if (row < NTOK) kv = *(const bf16x8*)(Kb + row * HDIM + c8);
        *(bf16x8*)(&Ksm[row][c8]) = kv;
      }
    }
#pragma unroll
    for (int r0 = 0; r0 < 384; r0 += 64) {
      int row = r0 + rb;
      if (row < NPAD) {
        bf16x8 vv = z8;
        if (row < NTOK) vv = *(const bf16x8*)(Vb + row * HDIM + c8);
        // pi(row): k-slot = ((m&16)>>2) | ((m&12)<<1) | (m&3) within 32-block
        int p = (row & ~31) | ((row & 12) << 1) | ((row & 16) >> 2) | (row & 3);
#pragma unroll
        for (int i = 0; i < 8; ++i) Vp[c8 + i][p] = vv[i];
      }
    }
  }
  __syncthreads();

  for (int qt = 0; qt < 6; ++qt) {
    const int q0 = qt * 64 + wave * 16;
    if (q0 >= NTOK) continue;
    const int qn = q0 + lr;
    const int qidx = (qn < NTOK) ? qn : (NTOK - 1);
    // Q B-frag: col=q=lr, k = channel 8*lg+i (clamped row; invalid cols unused)
    bf16x8 qf;
    {
      const float* qp = x_up + ((size_t)b * NTOK + qidx) * DIM + h * HDIM + koff;
      f32x4 v0 = *(const f32x4*)qp;
      f32x4 v1 = *(const f32x4*)(qp + 4);
#pragma unroll
      for (int i = 0; i < 4; ++i) {
        qf[i] = f2bf(v0[i] * SCALE);
        qf[i + 4] = f2bf(v1[i] * SCALE);
      }
    }
    // S^T tiles: s[j] = K_j * Q   (A=K: row=key=lr, k=ch; B=Q)
    f32x4 s[22];
#pragma unroll
    for (int j = 0; j < 22; ++j) {
      bf16x8 kf = *(const bf16x8*)(&Ksm[j * 16 + lr][koff]);
      s[j] = MFMA16(kf, qf, zero4);
    }
    // softmax over m: vector bias+mask add (f32x4 loads, pad handles tail),
    // row max (2 shfls), exp, sum (2 shfls), normalize before bf16 pack.
    const float* bq = bias_q4 + (size_t)h * MG * GSTRIDE + (size_t)lg * GSTRIDE +
                      qidx * 4;
    const float* mq = mask_q4 + (size_t)win * MG * GSTRIDE + (size_t)lg * GSTRIDE +
                      qidx * 4;
    float mx = -1e30f;
#pragma unroll
    for (int j = 0; j < 22; ++j) {
      f32x4 bv = *(const f32x4*)(bq + (size_t)j * 4 * GSTRIDE);
      f32x4 mv = *(const f32x4*)(mq + (size_t)j * 4 * GSTRIDE);
      s[j] += bv + mv;
#pragma unroll
      for (int r = 0; r < 4; ++r) mx = fmaxf(mx, s[j][r]);
    }
    mx = fmaxf(mx, __shfl_xor(mx, 16));
    mx = fmaxf(mx, __shfl_xor(mx, 32));
    float sum = 0.f;
#pragma unroll
    for (int j = 0; j < 22; ++j) {
#pragma unroll
      for (int r = 0; r < 4; ++r) {
        float p = __expf(s[j][r] - mx);
        s[j][r] = p;
        sum += p;
      }
    }
    sum += __shfl_xor(sum, 16);
    sum += __shfl_xor(sum, 32);
    const float inv = 1.0f / sum;
    i32x4 up4[11];
#pragma unroll
    for (int j = 0; j < 22; ++j) {
      up4[j >> 1][(j & 1) * 2 + 0] = pack2(s[j][0] * inv, s[j][1] * inv);
      up4[j >> 1][(j & 1) * 2 + 1] = pack2(s[j][2] * inv, s[j][3] * inv);
    }

    // O^T = V^T_pi * P : A-frag from Vp (b128), B-frag = packed P registers
    f32x4 o0 = zero4;
    f32x4 o1 = zero4;
#pragma unroll
    for (int kt = 0; kt < 11; ++kt) {
      bf16x8 pf = __builtin_bit_cast(bf16x8, up4[kt]);
      bf16x8 a0 = *(const bf16x8*)(&Vp[lr][kt * 32 + koff]);
      bf16x8 a1 = *(const bf16x8*)(&Vp[16 + lr][kt * 32 + koff]);
      o0 = MFMA16(a0, pf, o0);
      o1 = MFMA16(a1, pf, o1);
    }
    // lane holds O[q=lr][d = 4*lg + r (+16)]; already normalized; pack+store
    if (qn < NTOK) {
      short* op = attn_out + ((size_t)b * NTOK + qn) * DIM + h * HDIM + 4 * lg;
      *(int*)(op + 0) = pack2(o0[0], o0[1]);
      *(int*)(op + 2) = pack2(o0[2], o0[3]);
      *(int*)(op + 16) = pack2(o1[0], o1[1]);
      *(int*)(op + 18) = pack2(o1[2], o1[3]);
    }
  }
}

// ---------- kernel 3: out = (attn + pos) @ w_proj^T + b_proj ----------------
__global__ __launch_bounds__(256) void out_proj_kernel(
    const short* __restrict__ Xa, const float* __restrict__ pos,
    const float* __restrict__ W, const float* __restrict__ bpr,
    float* __restrict__ out) {
  __shared__ short As[128][40];
  __shared__ short Bs[128][40];
  const int tid = threadIdx.x;
  const int n0 = blockIdx.x * 128;
  const int m0 = blockIdx.y * 128;
  const int lane = tid & 63;
  const int wave = tid >> 6;
  const int wm = (wave >> 1) * 64;
  const int wn = (wave & 1) * 64;
  const int lr = lane & 15;
  const int lk = (lane >> 4) * 8;
  const int c4 = (tid & 7) * 4;
  const int rbase = tid >> 3;
  const f32x4 zero4 = {0.f, 0.f, 0.f, 0.f};

  f32x4 acc[4][4];
#pragma unroll
  for (int m = 0; m < 4; ++m)
#pragma unroll
    for (int n = 0; n < 4; ++n) acc[m][n] = zero4;

  for (int kk = 0; kk < 12; ++kk) {
    __syncthreads();
#pragma unroll
    for (int i = 0; i < 4; ++i) {
      int row = rbase + i * 32;
      size_t goff = (size_t)(m0 + row) * DIM + kk * 32 + c4;
      bf16x4 a4 = *(const bf16x4*)(Xa + goff);
      f32x4 p = *(const f32x4*)(pos + goff);
      bf16x4 s4;
#pragma unroll
      for (int j = 0; j < 4; ++j) s4[j] = f2bf(bf2f(a4[j]) + p[j]);
      *(bf16x4*)(&As[row][c4]) = s4;
    }
#pragma unroll
    for (int i = 0; i < 4; ++i) {
      int row = rbase + i * 32;
      f32x4 v = *(const f32x4*)(W + (size_t)(n0 + row) * DIM + kk * 32 + c4);
      bf16x4 s4;
#pragma unroll
      for (int j = 0; j < 4; ++j) s4[j] = f2bf(v[j]);
      *(bf16x4*)(&Bs[row][c4]) = s4;
    }
    __syncthreads();
    bf16x8 af[4], bf[4];
#pragma unroll
    for (int m = 0; m < 4; ++m) af[m] = *(const bf16x8*)(&As[wm + m * 16 + lr][lk]);
#pragma unroll
    for (int n = 0; n < 4; ++n) bf[n] = *(const bf16x8*)(&Bs[wn + n * 16 + lr][lk]);
#pragma unroll
    for (int m = 0; m < 4; ++m)
#pragma unroll
      for (int n = 0; n < 4; ++n) acc[m][n] = MFMA16(af[m], bf[n], acc[m][n]);
  }

  const int rq = (lane >> 4) * 4;
#pragma unroll
  for (int n = 0; n < 4; ++n) {
    int gcol = n0 + wn + n * 16 + lr;
    float bias = bpr[gcol];
#pragma unroll
    for (int m = 0; m < 4; ++m) {
#pragma unroll
      for (int r = 0; r < 4; ++r) {
        int grow = m0 + wm + m * 16 + rq + r;
        out[(size_t)grow * DIM + gcol] = acc[m][n][r] + bias;
      }
    }
  }
}

extern "C" void kernel_launch(void* const* d_in, const int* in_sizes, int n_in,
                              void* d_out, int out_size, void* d_ws, size_t ws_size,
                              hipStream_t stream) {
  const float* skip = (const float*)d_in[0];
  const float* x_up = (const float*)d_in[1];
  const float* pos = (const float*)d_in[2];
  const float* mask = (const float*)d_in[3];
  const float* w_kv = (const float*)d_in[4];
  const float* b_kv = (const float*)d_in[5];
  const float* w_proj = (const float*)d_in[6];
  const float* b_proj = (const float*)d_in[7];
  const float* bias_table = (const float*)d_in[8];
  const int* rpi = (const int*)d_in[9];
  float* out = (float*)d_out;

  char* ws = (char*)d_ws;
  const size_t kv_bytes = (size_t)BATCH * NHEAD * NTOK * HDIM * 2;   // 33,718,272
  const size_t bias_bytes = (size_t)NHEAD * MG * NTOK * 4 * 4;       //  5,795,328
  const size_t mask_bytes = (size_t)NWIN * MG * NTOK * 4 * 4;        // 30,908,416
  short* Kws = (short*)ws;
  short* Vws = (short*)(ws + kv_bytes);
  float* bias_q4 = (float*)(ws + 2 * kv_bytes);
  float* mask_q4 = (float*)(ws + 2 * kv_bytes + bias_bytes);
  short* attn_ws = (short*)(ws + 2 * kv_bytes + bias_bytes + mask_bytes);

  const int bias_total = NHEAD * MG * NTOK * 4;
  const int mask_total = NWIN * MG * NTOK * 4;
  bias_pk_kernel<<<dim3((bias_total + 255) / 256), dim3(256), 0, stream>>>(
      bias_table, rpi, bias_q4);
  mask_pk_kernel<<<dim3((mask_total + 255) / 256), dim3(256), 0, stream>>>(
      mask, mask_q4);
  kv_proj_kernel<<<dim3(6, 343), dim3(256), 0, stream>>>(skip, w_kv, b_kv, Kws, Vws);
  attn_kernel<<<dim3(BATCH * NHEAD), dim3(256), 0, stream>>>(x_up, mask_q4, bias_q4,
                                                             Kws, Vws, attn_ws);
  out_proj_kernel<<<dim3(3, 343), dim3(256), 0, stream>>>(attn_ws, pos, w_proj,
                                                          b_proj, out);
}

// Round 10
// 349.133 us; speedup vs baseline: 2.3211x; 1.1089x over previous
//
#include <hip/hip_runtime.h>

#define NTOK 343
#define NPAD 352
#define DIM 384
#define NHEAD 12
#define HDIM 32
#define NWIN 64
#define BATCH 128
#define SCALE 0.17677669529663687f
#define NN 117649   // 343*343
#define MG 88       // NPAD/4 m-groups
#define GSTRIDE 1372  // NTOK*4 floats per m-group

typedef __attribute__((ext_vector_type(8))) short bf16x8;
typedef __attribute__((ext_vector_type(4))) short bf16x4;
typedef __attribute__((ext_vector_type(4))) float f32x4;
typedef __attribute__((ext_vector_type(4))) int i32x4;

static __device__ inline short f2bf(float f) {
  union { float f; unsigned u; } v; v.f = f;
  unsigned r = v.u + 0x7fffu + ((v.u >> 16) & 1u);
  return (short)(r >> 16);
}
static __device__ inline float bf2f(short s) {
  union { unsigned u; float f; } v; v.u = ((unsigned)(unsigned short)s) << 16;
  return v.f;
}
// pack two f32 -> one int of 2 bf16 (lo in low half), RTNE via f2bf
static __device__ inline int pack2(float lo, float hi) {
  return (int)((unsigned)(unsigned short)f2bf(lo) |
               ((unsigned)(unsigned short)f2bf(hi) << 16));
}

#define MFMA16(a, b, c) __builtin_amdgcn_mfma_f32_16x16x32_bf16((a), (b), (c), 0, 0, 0)

// ---- kernel 0a: bias_q4[h][g][q][r] = table[rpi[q][g*4+r]][h], pad=-1e30 ----
__global__ __launch_bounds__(256) void bias_pk_kernel(
    const float* __restrict__ table, const int* __restrict__ rpi,
    float* __restrict__ bias_q4) {
  int idx = blockIdx.x * 256 + threadIdx.x;
  const int total = NHEAD * MG * NTOK * 4;
  if (idx >= total) return;
  int r = idx & 3;
  int t = idx >> 2;
  int q = t % NTOK;
  int u = t / NTOK;
  int g = u % MG;
  int h = u / MG;
  int m = g * 4 + r;
  bias_q4[idx] = (m < NTOK) ? table[rpi[q * NTOK + m] * NHEAD + h] : -1e30f;
}

// ---- kernel 0b: mask_q4[w][g][q][r] = mask[w][q][g*4+r], pad=0 --------------
__global__ __launch_bounds__(256) void mask_pk_kernel(
    const float* __restrict__ in, float* __restrict__ mask_q4) {
  int idx = blockIdx.x * 256 + threadIdx.x;
  const int total = NWIN * MG * NTOK * 4;
  if (idx >= total) return;
  int r = idx & 3;
  int t = idx >> 2;
  int q = t % NTOK;
  int u = t / NTOK;
  int g = u % MG;
  int w = u / MG;
  int m = g * 4 + r;
  mask_q4[idx] = (m < NTOK) ? in[(size_t)w * NN + q * NTOK + m] : 0.0f;
}

// ---- kernel 0c: skip f32 -> bf16 (A-operand for kv_proj) -------------------
__global__ __launch_bounds__(256) void cvt_skip_kernel(
    const float* __restrict__ in, short* __restrict__ out, int n8) {
  int i = blockIdx.x * 256 + threadIdx.x;
  if (i >= n8) return;
  f32x4 a = *(const f32x4*)(in + (size_t)i * 8);
  f32x4 b = *(const f32x4*)(in + (size_t)i * 8 + 4);
  bf16x8 o;
#pragma unroll
  for (int j = 0; j < 4; ++j) {
    o[j] = f2bf(a[j]);
    o[j + 4] = f2bf(b[j]);
  }
  *(bf16x8*)(out + (size_t)i * 8) = o;
}

// ---------- kernel 1: kv = skip_bf @ w_kv^T + b_kv -> K_ws/V_ws (bf16) ------
__global__ __launch_bounds__(256) void kv_proj_kernel(
    const short* __restrict__ Xbf, const float* __restrict__ W,
    const float* __restrict__ bkv, short* __restrict__ Kws,
    short* __restrict__ Vws) {
  __shared__ short As[128][40];
  __shared__ short Bs[128][40];
  const int tid = threadIdx.x;
  const int n0 = blockIdx.x * 128;
  const int m0 = blockIdx.y * 128;
  const int lane = tid & 63;
  const int wave = tid >> 6;
  const int wm = (wave >> 1) * 64;
  const int wn = (wave & 1) * 64;
  const int lr = lane & 15;
  const int lk = (lane >> 4) * 8;
  const int c4 = (tid & 7) * 4;
  const int rbase = tid >> 3;
  const int arow = tid >> 2;        // 0..63
  const int acol8 = (tid & 3) * 8;  // 0,8,16,24
  const f32x4 zero4 = {0.f, 0.f, 0.f, 0.f};

  f32x4 acc[4][4];
#pragma unroll
  for (int m = 0; m < 4; ++m)
#pragma unroll
    for (int n = 0; n < 4; ++n) acc[m][n] = zero4;

  for (int kk = 0; kk < 12; ++kk) {
    __syncthreads();
    // A: direct bf16x8 copy (no conversion)
    *(bf16x8*)(&As[arow][acol8]) =
        *(const bf16x8*)(Xbf + (size_t)(m0 + arow) * DIM + kk * 32 + acol8);
    *(bf16x8*)(&As[arow + 64][acol8]) =
        *(const bf16x8*)(Xbf + (size_t)(m0 + arow + 64) * DIM + kk * 32 + acol8);
    // B: f32 -> bf16 (W is small, L2-resident)
#pragma unroll
    for (int i = 0; i < 4; ++i) {
      int row = rbase + i * 32;
      f32x4 v = *(const f32x4*)(W + (size_t)(n0 + row) * DIM + kk * 32 + c4);
      bf16x4 s4;
#pragma unroll
      for (int j = 0; j < 4; ++j) s4[j] = f2bf(v[j]);
      *(bf16x4*)(&Bs[row][c4]) = s4;
    }
    __syncthreads();
    bf16x8 af[4], bf[4];
#pragma unroll
    for (int m = 0; m < 4; ++m) af[m] = *(const bf16x8*)(&As[wm + m * 16 + lr][lk]);
#pragma unroll
    for (int n = 0; n < 4; ++n) bf[n] = *(const bf16x8*)(&Bs[wn + n * 16 + lr][lk]);
#pragma unroll
    for (int m = 0; m < 4; ++m)
#pragma unroll
      for (int n = 0; n < 4; ++n) acc[m][n] = MFMA16(af[m], bf[n], acc[m][n]);
  }

  const int rq = (lane >> 4) * 4;
#pragma unroll
  for (int n = 0; n < 4; ++n) {
    int gcol = n0 + wn + n * 16 + lr;
    float bias = bkv[gcol];
    int c = (gcol >= DIM) ? (gcol - DIM) : gcol;  // gcol % 384
    int h = c >> 5;
    int hd = c & 31;
    short* dst = (gcol < DIM) ? Kws : Vws;
#pragma unroll
    for (int m = 0; m < 4; ++m) {
#pragma unroll
      for (int r = 0; r < 4; ++r) {
        int grow = m0 + wm + m * 16 + rq + r;
        int bb = grow / NTOK;
        int tok = grow - bb * NTOK;
        dst[(((size_t)bb * NHEAD + h) * NTOK + tok) * HDIM + hd] =
            f2bf(acc[m][n][r] + bias);
      }
    }
  }
}

// ---------- kernel 2: fused attention per (b, h) — swapped-QK^T form --------
// Win-grouped XCD swizzle; f32x4 bias/mask loads; +pos fused into epilogue;
// setprio around MFMA clusters (independent waves -> m191 attn case).
__global__ __launch_bounds__(256, 3) void attn_kernel(
    const float* __restrict__ x_up, const float* __restrict__ mask_q4,
    const float* __restrict__ bias_q4, const short* __restrict__ Kws,
    const short* __restrict__ Vws, const float* __restrict__ pos,
    short* __restrict__ attn_out) {
  __shared__ short Ksm[NPAD][40];      // K[key][ch], row stride 80B
  __shared__ short Vp[HDIM][NPAD + 8]; // V^T[ch][pi(key)], row stride 720B
  const int bid = blockIdx.x;
  const int xcd = bid & 7;
  const int jj = bid >> 3;                 // 0..191
  const int win = xcd * 8 + jj / 24;       // 0..63, pinned to xcd
  const int rep = jj - (jj / 24) * 24;     // 0..23
  const int h = rep % NHEAD;
  const int b = win + ((rep >= NHEAD) ? 64 : 0);
  const int tid = threadIdx.x;
  const int wave = tid >> 6;
  const int lane = tid & 63;
  const int lr = lane & 15;
  const int lg = lane >> 4;
  const int koff = lg * 8;
  const f32x4 zero4 = {0.f, 0.f, 0.f, 0.f};

  const short* Kb = Kws + ((size_t)b * NHEAD + h) * NTOK * HDIM;
  const short* Vb = Vws + ((size_t)b * NHEAD + h) * NTOK * HDIM;
  {
    const int c8 = (tid & 3) * 8;
    const int rb = tid >> 2;
    const bf16x8 z8 = {0, 0, 0, 0, 0, 0, 0, 0};
#pragma unroll
    for (int r0 = 0; r0 < 384; r0 += 64) {
      int row = r0 + rb;
      if (row < NPAD) {
        bf16x8 kv = z8;
        if (row < NTOK) kv = *(const bf16x8*)(Kb + row * HDIM + c8);
        *(bf16x8*)(&Ksm[row][c8]) = kv;
      }
    }
#pragma unroll
    for (int r0 = 0; r0 < 384; r0 += 64) {
      int row = r0 + rb;
      if (row < NPAD) {
        bf16x8 vv = z8;
        if (row < NTOK) vv = *(const bf16x8*)(Vb + row * HDIM + c8);
        // pi(row): k-slot = ((m&16)>>2) | ((m&12)<<1) | (m&3) within 32-block
        int p = (row & ~31) | ((row & 12) << 1) | ((row & 16) >> 2) | (row & 3);
#pragma unroll
        for (int i = 0; i < 8; ++i) Vp[c8 + i][p] = vv[i];
      }
    }
  }
  __syncthreads();

  for (int qt = 0; qt < 6; ++qt) {
    const int q0 = qt * 64 + wave * 16;
    if (q0 >= NTOK) continue;
    const int qn = q0 + lr;
    const int qidx = (qn < NTOK) ? qn : (NTOK - 1);
    // Q B-frag: col=q=lr, k = channel 8*lg+i (clamped row; invalid cols unused)
    bf16x8 qf;
    {
      const float* qp = x_up + ((size_t)b * NTOK + qidx) * DIM + h * HDIM + koff;
      f32x4 v0 = *(const f32x4*)qp;
      f32x4 v1 = *(const f32x4*)(qp + 4);
#pragma unroll
      for (int i = 0; i < 4; ++i) {
        qf[i] = f2bf(v0[i] * SCALE);
        qf[i + 4] = f2bf(v1[i] * SCALE);
      }
    }
    // S^T tiles: s[j] = K_j * Q   (A=K: row=key=lr, k=ch; B=Q)
    f32x4 s[22];
    __builtin_amdgcn_s_setprio(1);
#pragma unroll
    for (int j = 0; j < 22; ++j) {
      bf16x8 kf = *(const bf16x8*)(&Ksm[j * 16 + lr][koff]);
      s[j] = MFMA16(kf, qf, zero4);
    }
    __builtin_amdgcn_s_setprio(0);
    // softmax over m: vector bias+mask add (f32x4 loads, pad handles tail),
    // row max (2 shfls), exp, sum (2 shfls), normalize before bf16 pack.
    const float* bq = bias_q4 + (size_t)h * MG * GSTRIDE + (size_t)lg * GSTRIDE +
                      qidx * 4;
    const float* mq = mask_q4 + (size_t)win * MG * GSTRIDE + (size_t)lg * GSTRIDE +
                      qidx * 4;
    float mx = -1e30f;
#pragma unroll
    for (int j = 0; j < 22; ++j) {
      f32x4 bv = *(const f32x4*)(bq + (size_t)j * 4 * GSTRIDE);
      f32x4 mv = *(const f32x4*)(mq + (size_t)j * 4 * GSTRIDE);
      s[j] += bv + mv;
#pragma unroll
      for (int r = 0; r < 4; ++r) mx = fmaxf(mx, s[j][r]);
    }
    mx = fmaxf(mx, __shfl_xor(mx, 16));
    mx = fmaxf(mx, __shfl_xor(mx, 32));
    float sum = 0.f;
#pragma unroll
    for (int j = 0; j < 22; ++j) {
#pragma unroll
      for (int r = 0; r < 4; ++r) {
        float p = __expf(s[j][r] - mx);
        s[j][r] = p;
        sum += p;
      }
    }
    sum += __shfl_xor(sum, 16);
    sum += __shfl_xor(sum, 32);
    const float inv = 1.0f / sum;
    i32x4 up4[11];
#pragma unroll
    for (int j = 0; j < 22; ++j) {
      up4[j >> 1][(j & 1) * 2 + 0] = pack2(s[j][0] * inv, s[j][1] * inv);
      up4[j >> 1][(j & 1) * 2 + 1] = pack2(s[j][2] * inv, s[j][3] * inv);
    }

    // O^T = V^T_pi * P : A-frag from Vp (b128), B-frag = packed P registers
    f32x4 o0 = zero4;
    f32x4 o1 = zero4;
    __builtin_amdgcn_s_setprio(1);
#pragma unroll
    for (int kt = 0; kt < 11; ++kt) {
      bf16x8 pf = __builtin_bit_cast(bf16x8, up4[kt]);
      bf16x8 a0 = *(const bf16x8*)(&Vp[lr][kt * 32 + koff]);
      bf16x8 a1 = *(const bf16x8*)(&Vp[16 + lr][kt * 32 + koff]);
      o0 = MFMA16(a0, pf, o0);
      o1 = MFMA16(a1, pf, o1);
    }
    __builtin_amdgcn_s_setprio(0);
    // lane holds O[q=lr][d = 4*lg + r (+16)]; O already normalized (P*inv).
    // Add pos_embed (fused), pack+store.
    if (qn < NTOK) {
      const float* pp = pos + ((size_t)b * NTOK + qn) * DIM + h * HDIM + 4 * lg;
      f32x4 p0 = *(const f32x4*)pp;
      f32x4 p1 = *(const f32x4*)(pp + 16);
      short* op = attn_out + ((size_t)b * NTOK + qn) * DIM + h * HDIM + 4 * lg;
      *(int*)(op + 0) = pack2(o0[0] + p0[0], o0[1] + p0[1]);
      *(int*)(op + 2) = pack2(o0[2] + p0[2], o0[3] + p0[3]);
      *(int*)(op + 16) = pack2(o1[0] + p1[0], o1[1] + p1[1]);
      *(int*)(op + 18) = pack2(o1[2] + p1[2], o1[3] + p1[3]);
    }
  }
}

// ---------- kernel 3: out = Xa @ w_proj^T + b_proj (Xa = attn+pos, bf16) ----
__global__ __launch_bounds__(256) void out_proj_kernel(
    const short* __restrict__ Xa, const float* __restrict__ W,
    const float* __restrict__ bpr, float* __restrict__ out) {
  __shared__ short As[128][40];
  __shared__ short Bs[128][40];
  const int tid = threadIdx.x;
  const int n0 = blockIdx.x * 128;
  const int m0 = blockIdx.y * 128;
  const int lane = tid & 63;
  const int wave = tid >> 6;
  const int wm = (wave >> 1) * 64;
  const int wn = (wave & 1) * 64;
  const int lr = lane & 15;
  const int lk = (lane >> 4) * 8;
  const int c4 = (tid & 7) * 4;
  const int rbase = tid >> 3;
  const int arow = tid >> 2;
  const int acol8 = (tid & 3) * 8;
  const f32x4 zero4 = {0.f, 0.f, 0.f, 0.f};

  f32x4 acc[4][4];
#pragma unroll
  for (int m = 0; m < 4; ++m)
#pragma unroll
    for (int n = 0; n < 4; ++n) acc[m][n] = zero4;

  for (int kk = 0; kk < 12; ++kk) {
    __syncthreads();
    *(bf16x8*)(&As[arow][acol8]) =
        *(const bf16x8*)(Xa + (size_t)(m0 + arow) * DIM + kk * 32 + acol8);
    *(bf16x8*)(&As[arow + 64][acol8]) =
        *(const bf16x8*)(Xa + (size_t)(m0 + arow + 64) * DIM + kk * 32 + acol8);
#pragma unroll
    for (int i = 0; i < 4; ++i) {
      int row = rbase + i * 32;
      f32x4 v = *(const f32x4*)(W + (size_t)(n0 + row) * DIM + kk * 32 + c4);
      bf16x4 s4;
#pragma unroll
      for (int j = 0; j < 4; ++j) s4[j] = f2bf(v[j]);
      *(bf16x4*)(&Bs[row][c4]) = s4;
    }
    __syncthreads();
    bf16x8 af[4], bf[4];
#pragma unroll
    for (int m = 0; m < 4; ++m) af[m] = *(const bf16x8*)(&As[wm + m * 16 + lr][lk]);
#pragma unroll
    for (int n = 0; n < 4; ++n) bf[n] = *(const bf16x8*)(&Bs[wn + n * 16 + lr][lk]);
#pragma unroll
    for (int m = 0; m < 4; ++m)
#pragma unroll
      for (int n = 0; n < 4; ++n) acc[m][n] = MFMA16(af[m], bf[n], acc[m][n]);
  }

  const int rq = (lane >> 4) * 4;
#pragma unroll
  for (int n = 0; n < 4; ++n) {
    int gcol = n0 + wn + n * 16 + lr;
    float bias = bpr[gcol];
#pragma unroll
    for (int m = 0; m < 4; ++m) {
#pragma unroll
      for (int r = 0; r < 4; ++r) {
        int grow = m0 + wm + m * 16 + rq + r;
        out[(size_t)grow * DIM + gcol] = acc[m][n][r] + bias;
      }
    }
  }
}

extern "C" void kernel_launch(void* const* d_in, const int* in_sizes, int n_in,
                              void* d_out, int out_size, void* d_ws, size_t ws_size,
                              hipStream_t stream) {
  const float* skip = (const float*)d_in[0];
  const float* x_up = (const float*)d_in[1];
  const float* pos = (const float*)d_in[2];
  const float* mask = (const float*)d_in[3];
  const float* w_kv = (const float*)d_in[4];
  const float* b_kv = (const float*)d_in[5];
  const float* w_proj = (const float*)d_in[6];
  const float* b_proj = (const float*)d_in[7];
  const float* bias_table = (const float*)d_in[8];
  const int* rpi = (const int*)d_in[9];
  float* out = (float*)d_out;

  char* ws = (char*)d_ws;
  const size_t kv_bytes = (size_t)BATCH * NHEAD * NTOK * HDIM * 2;   // 33,718,272
  const size_t bias_bytes = (size_t)NHEAD * MG * NTOK * 4 * 4;       //  5,795,328
  const size_t mask_bytes = (size_t)NWIN * MG * NTOK * 4 * 4;        // 30,908,416
  short* Kws = (short*)ws;
  short* Vws = (short*)(ws + kv_bytes);
  float* bias_q4 = (float*)(ws + 2 * kv_bytes);
  float* mask_q4 = (float*)(ws + 2 * kv_bytes + bias_bytes);
  // skip_bf and attn_ws alias: cvt_skip->kv_proj finish before attn writes it
  short* skip_bf = (short*)(ws + 2 * kv_bytes + bias_bytes + mask_bytes);
  short* attn_ws = skip_bf;

  const int bias_total = NHEAD * MG * NTOK * 4;
  const int mask_total = NWIN * MG * NTOK * 4;
  const int n8 = BATCH * NTOK * DIM / 8;  // 2,107,392
  bias_pk_kernel<<<dim3((bias_total + 255) / 256), dim3(256), 0, stream>>>(
      bias_table, rpi, bias_q4);
  mask_pk_kernel<<<dim3((mask_total + 255) / 256), dim3(256), 0, stream>>>(
      mask, mask_q4);
  cvt_skip_kernel<<<dim3((n8 + 255) / 256), dim3(256), 0, stream>>>(
      skip, skip_bf, n8);
  kv_proj_kernel<<<dim3(6, 343), dim3(256), 0, stream>>>(skip_bf, w_kv, b_kv,
                                                         Kws, Vws);
  attn_kernel<<<dim3(BATCH * NHEAD), dim3(256), 0, stream>>>(
      x_up, mask_q4, bias_q4, Kws, Vws, pos, attn_ws);
  out_proj_kernel<<<dim3(3, 343), dim3(256), 0, stream>>>(attn_ws, w_proj,
                                                          b_proj, out);
}